// Round 12
// baseline (274.121 us; speedup 1.0000x reference)
//
#include <hip/hip_runtime.h>
#include <hip/hip_bf16.h>

#define BN 4096
#define DD 128
#define SD 136          // padded bf16 row stride (elems)
#define NCLS 64
#define MARGIN_F 1.0f
#define NBLK 512        // persistent grid: 2 blocks/CU x 256 CU, all resident
#define NSLOT 64        // negp partial slots per row (32 bj x 2 wc)

typedef __attribute__((ext_vector_type(8))) short bf16x8;
typedef __attribute__((ext_vector_type(4))) float f32x4;

__device__ __forceinline__ unsigned short f2bf(float f) {
    __hip_bfloat16 h = __float2bfloat16(f);
    return *reinterpret_cast<unsigned short*>(&h);
}

// zero the barrier counters each call (tiny kernel; no memset node)
__global__ __launch_bounds__(64) void zero_kernel(int* __restrict__ cnt) {
    if (threadIdx.x < 8) cnt[threadIdx.x] = 0;
}

// device-scope grid barrier: arrive (release) + thread-0 spin (acquire)
__device__ __forceinline__ void grid_barrier(int* cnt, int tid) {
    __syncthreads();
    if (tid == 0) {
        __threadfence();
        atomicAdd(cnt, 1);
        while (__hip_atomic_load(cnt, __ATOMIC_ACQUIRE, __HIP_MEMORY_SCOPE_AGENT) < NBLK)
            __builtin_amdgcn_s_sleep(2);
        __threadfence();
    }
    __syncthreads();
}

__global__ __launch_bounds__(256, 2) void mega_kernel(
    const float* __restrict__ score,
    const int* __restrict__ tgt,
    unsigned short* __restrict__ sbf,
    float* __restrict__ mag,
    float* __restrict__ neg,
    float* __restrict__ negp,
    float2* __restrict__ part,
    int* __restrict__ cnt,
    float* __restrict__ out)
{
    const int b = blockIdx.x;
    const int tid = threadIdx.x;
    const int wid = tid >> 6, lane = tid & 63;
    const int lhi = lane >> 4, llo = lane & 15;

    __shared__ int slist[256];
    __shared__ int wsum[4];
    __shared__ int snc;
    __shared__ float2 wpart[4];

    // ================= P0: prep — 8 rows/block: fp32->bf16 + mag =================
    {
        const int row = b * 8 + wid * 2 + (lane >> 5);
        const int l32 = lane & 31;
        float4 v = *reinterpret_cast<const float4*>(score + (size_t)row * DD + l32 * 4);
        ushort4 u;
        u.x = f2bf(v.x); u.y = f2bf(v.y); u.z = f2bf(v.z); u.w = f2bf(v.w);
        *reinterpret_cast<ushort4*>(sbf + (size_t)row * SD + l32 * 4) = u;
        float s = v.x * v.x + v.y * v.y + v.z * v.z + v.w * v.w;
        #pragma unroll
        for (int o = 16; o > 0; o >>= 1) s += __shfl_xor(s, o);
        if (l32 == 0) mag[row] = s;
    }
    grid_barrier(&cnt[0], tid);

    // ================= P1: negsum — 2 tile-jobs/block (in-kernel amortization) ====
    #pragma unroll 1
    for (int job = b; job < 1024; job += NBLK) {
        const int bi = job & 31, bj = job >> 5;
        const int wr = wid >> 1, wc = wid & 1;
        const int i0 = bi * 128 + wr * 64;
        const int j0 = bj * 128 + wc * 64;

        f32x4 acc[4][4] = {};
        #pragma unroll
        for (int kk = 0; kk < 4; ++kk) {
            const int koff = kk * 32 + lhi * 8;
            bf16x8 a[4], bb[4];
            #pragma unroll
            for (int m = 0; m < 4; ++m)
                a[m] = *reinterpret_cast<const bf16x8*>(sbf + (size_t)(i0 + m * 16 + llo) * SD + koff);
            #pragma unroll
            for (int n = 0; n < 4; ++n)
                bb[n] = *reinterpret_cast<const bf16x8*>(sbf + (size_t)(j0 + n * 16 + llo) * SD + koff);
            #pragma unroll
            for (int m = 0; m < 4; ++m)
                #pragma unroll
                for (int n = 0; n < 4; ++n)
                    acc[m][n] = __builtin_amdgcn_mfma_f32_16x16x32_bf16(a[m], bb[n], acc[m][n], 0, 0, 0);
        }

        float magj[4]; int tj[4];
        #pragma unroll
        for (int n = 0; n < 4; ++n) {
            const int j = j0 + n * 16 + llo;
            magj[n] = mag[j];
            tj[n] = tgt[j];
        }

        const int slot = bj * 2 + wc;
        #pragma unroll
        for (int m = 0; m < 4; ++m) {
            const int ibase = i0 + m * 16 + lhi * 4;
            f32x4 magi = *reinterpret_cast<const f32x4*>(mag + ibase);
            int4 ti4 = *reinterpret_cast<const int4*>(tgt + ibase);
            const int* tip = &ti4.x;
            f32x4 rs = {0.0f, 0.0f, 0.0f, 0.0f};
            #pragma unroll
            for (int r = 0; r < 4; ++r) {
                const int ti = tip[r];
                float s = 0.0f;
                #pragma unroll
                for (int n = 0; n < 4; ++n) {
                    float d2 = fmaxf(magi[r] + magj[n] - 2.0f * acc[m][n][r], 0.0f);
                    float dist = __builtin_amdgcn_sqrtf(d2);
                    s += (ti != tj[n]) ? __expf(MARGIN_F - dist) : 0.0f;
                }
                #pragma unroll
                for (int o = 1; o < 16; o <<= 1) s += __shfl_xor(s, o);
                rs[r] = s;
            }
            if (llo == 0)
                *reinterpret_cast<f32x4*>(negp + (size_t)slot * BN + ibase) = rs;
        }
    }
    grid_barrier(&cnt[1], tid);

    // ================= P2: fold 64 slots -> neg (8 rows/block) ====================
    {
        const int i = b * 8 + (tid >> 5);
        const int l32 = tid & 31;
        float s = negp[(size_t)l32 * BN + i] + negp[(size_t)(l32 + 32) * BN + i];
        #pragma unroll
        for (int o = 16; o > 0; o >>= 1) s += __shfl_xor(s, o);
        if (l32 == 0) neg[i] = s;
    }
    grid_barrier(&cnt[2], tid);

    // ================= P3: per-class loss (blocks 0..63) ==========================
    if (b < NCLS) {
        const int c = b;
        int4 tv[4];
        #pragma unroll
        for (int k = 0; k < 4; ++k)
            tv[k] = *reinterpret_cast<const int4*>(tgt + tid * 16 + k * 4);
        int cnt2 = 0;
        #pragma unroll
        for (int k = 0; k < 4; ++k) {
            const int* q = &tv[k].x;
            #pragma unroll
            for (int e = 0; e < 4; ++e) cnt2 += (q[e] == c) ? 1 : 0;
        }
        int inc = cnt2;
        #pragma unroll
        for (int o = 1; o < 64; o <<= 1) {
            int u = __shfl_up(inc, o);
            if (lane >= o) inc += u;
        }
        if (lane == 63) wsum[wid] = inc;
        __syncthreads();
        int wpre = 0;
        #pragma unroll
        for (int w = 0; w < 4; ++w) wpre += (w < wid) ? wsum[w] : 0;
        if (tid == 255) snc = wpre + inc;
        int pos = wpre + inc - cnt2;
        #pragma unroll
        for (int k = 0; k < 4; ++k) {
            const int* q = &tv[k].x;
            #pragma unroll
            for (int e = 0; e < 4; ++e) {
                if (q[e] == c && pos < 256) { slist[pos] = tid * 16 + k * 4 + e; ++pos; }
            }
        }
        __syncthreads();
        const int n_c = snc;

        const int wr = wid >> 1, wc = wid & 1;
        const int p0 = wr * 64, q0 = wc * 64;

        float lsum = 0.0f, lcnt = 0.0f;
        const bool active = (n_c > 0) && (wc >= wr) && (p0 < n_c) && (q0 < n_c);
        if (active) {
            int opA[4], opB[4];
            #pragma unroll
            for (int m = 0; m < 4; ++m) {
                const int p = p0 + m * 16 + llo;
                opA[m] = slist[min(p, n_c - 1)];
            }
            #pragma unroll
            for (int n = 0; n < 4; ++n) {
                const int q = q0 + n * 16 + llo;
                opB[n] = slist[min(q, n_c - 1)];
            }
            f32x4 acc[4][4] = {};
            #pragma unroll
            for (int kk = 0; kk < 4; ++kk) {
                const int koff = kk * 32 + lhi * 8;
                bf16x8 a[4], bb[4];
                #pragma unroll
                for (int m = 0; m < 4; ++m)
                    a[m] = *reinterpret_cast<const bf16x8*>(sbf + (size_t)opA[m] * SD + koff);
                #pragma unroll
                for (int n = 0; n < 4; ++n)
                    bb[n] = *reinterpret_cast<const bf16x8*>(sbf + (size_t)opB[n] * SD + koff);
                #pragma unroll
                for (int m = 0; m < 4; ++m)
                    #pragma unroll
                    for (int n = 0; n < 4; ++n)
                        acc[m][n] = __builtin_amdgcn_mfma_f32_16x16x32_bf16(a[m], bb[n], acc[m][n], 0, 0, 0);
            }

            float magjv[4], nsj[4]; int qv[4];
            #pragma unroll
            for (int n = 0; n < 4; ++n) {
                qv[n] = q0 + n * 16 + llo;
                magjv[n] = mag[opB[n]];
                nsj[n] = neg[opB[n]];
            }

            #pragma unroll
            for (int m = 0; m < 4; ++m) {
                #pragma unroll
                for (int r = 0; r < 4; ++r) {
                    const int p = p0 + m * 16 + lhi * 4 + r;
                    const bool pv = (p < n_c);
                    const int io = slist[min(p, n_c - 1)];
                    const float magiv = mag[io];
                    const float nsi = neg[io];
                    #pragma unroll
                    for (int n = 0; n < 4; ++n) {
                        if (pv && qv[n] > p && qv[n] < n_c) {
                            float d2 = fmaxf(magiv + magjv[n] - 2.0f * acc[m][n][r], 0.0f);
                            float dist = __builtin_amdgcn_sqrtf(d2);
                            float ln = __logf(nsi + nsj[n]);
                            float uu = fmaxf(ln + dist, 0.0f);
                            lsum += uu * uu;
                            lcnt += 1.0f;
                        }
                    }
                }
            }
        }

        #pragma unroll
        for (int o = 32; o > 0; o >>= 1) {
            lsum += __shfl_xor(lsum, o);
            lcnt += __shfl_xor(lcnt, o);
        }
        if (lane == 0) wpart[wid] = make_float2(lsum, lcnt);
        __syncthreads();
        if (tid == 0) {
            float s = 0.0f, cc = 0.0f;
            #pragma unroll
            for (int w = 0; w < 4; ++w) { s += wpart[w].x; cc += wpart[w].y; }
            part[c] = make_float2(s, cc);
        }
    }
    grid_barrier(&cnt[3], tid);

    // ================= P4: finalize (block 0) =====================================
    if (b == 0 && tid < 64) {
        float2 p = part[tid];
        float s = p.x, c = p.y;
        #pragma unroll
        for (int o = 32; o > 0; o >>= 1) {
            s += __shfl_xor(s, o);
            c += __shfl_xor(c, o);
        }
        if (tid == 0) out[0] = s / (2.0f * fmaxf(c, 1.0f));
    }
}

extern "C" void kernel_launch(void* const* d_in, const int* in_sizes, int n_in,
                              void* d_out, int out_size, void* d_ws, size_t ws_size,
                              hipStream_t stream) {
    const float* score = (const float*)d_in[0];
    const int* tgt = (const int*)d_in[1];
    float* out = (float*)d_out;

    char* ws = (char*)d_ws;
    unsigned short* sbf = (unsigned short*)ws;               // 4096*136*2 ≈ 1.09 MB
    float* mag = (float*)(ws + (size_t)BN * SD * 2 + 64);    // 16 KB
    float* neg = mag + BN;                                   // 16 KB
    float* negp = neg + BN;                                  // 64*4096*4 = 1 MB
    float2* part = (float2*)(negp + (size_t)NSLOT * BN);     // 512 B
    int* cnt = (int*)(part + NCLS);                          // 8 ints (barrier counters)

    zero_kernel<<<1, 64, 0, stream>>>(cnt);
    mega_kernel<<<NBLK, 256, 0, stream>>>(score, tgt, sbf, mag, neg, negp, part, cnt, out);
}

// Round 13
// 78.765 us; speedup vs baseline: 3.4802x; 3.4802x over previous
//
#include <hip/hip_runtime.h>
#include <hip/hip_bf16.h>

#define BN 4096
#define DD 128
#define NCLS 64
#define MARGIN_F 1.0f
#define NSQ 1024        // 32x32 grid of 128x128 tiles
#define NSLOT 64        // negp partial slots per row (32 bj x 2 wc)

typedef __attribute__((ext_vector_type(8))) short bf16x8;
typedef __attribute__((ext_vector_type(4))) float f32x4;

__device__ __forceinline__ short f2bf(float f) {
    __hip_bfloat16 h = __float2bfloat16(f);
    return *reinterpret_cast<short*>(&h);
}

// load 8 fp32, accumulate sum-of-squares, return bf16x8 fragment
__device__ __forceinline__ bf16x8 load_cvt8(const float* __restrict__ p, float& ssq) {
    float4 u = *reinterpret_cast<const float4*>(p);
    float4 v = *reinterpret_cast<const float4*>(p + 4);
    ssq += u.x * u.x + u.y * u.y + u.z * u.z + u.w * u.w
         + v.x * v.x + v.y * v.y + v.z * v.z + v.w * v.w;
    bf16x8 f;
    f[0] = f2bf(u.x); f[1] = f2bf(u.y); f[2] = f2bf(u.z); f[3] = f2bf(u.w);
    f[4] = f2bf(v.x); f[5] = f2bf(v.y); f[6] = f2bf(v.z); f[7] = f2bf(v.w);
    return f;
}

// K1: neg partial sums, fully fused: reads READ-ONLY fp32 score directly
// (stays L2-warm across graph replays — no producer writes to invalidate),
// bf16 conversion + row norms computed in-register.
__global__ __launch_bounds__(256, 2) void negsum_kernel(
    const float* __restrict__ score,
    const int* __restrict__ tgt,
    float* __restrict__ negp)
{
    const int bid = blockIdx.x;
    const int tid = threadIdx.x;
    const int wid = tid >> 6, lane = tid & 63;
    const int bi = bid & 31, bj = bid >> 5;
    const int wr = wid >> 1, wc = wid & 1;
    const int i0 = bi * 128 + wr * 64;
    const int j0 = bj * 128 + wc * 64;
    const int lhi = lane >> 4, llo = lane & 15;

    f32x4 acc[4][4] = {};
    float amag[4] = {0.f, 0.f, 0.f, 0.f};   // partial ssq of A row i0+m*16+llo
    float bmag[4] = {0.f, 0.f, 0.f, 0.f};   // partial ssq of B row j0+n*16+llo
    #pragma unroll
    for (int kk = 0; kk < 4; ++kk) {
        const int ke = kk * 32 + lhi * 8;
        bf16x8 a[4], b[4];
        #pragma unroll
        for (int m = 0; m < 4; ++m)
            a[m] = load_cvt8(score + (size_t)(i0 + m * 16 + llo) * DD + ke, amag[m]);
        #pragma unroll
        for (int n = 0; n < 4; ++n)
            b[n] = load_cvt8(score + (size_t)(j0 + n * 16 + llo) * DD + ke, bmag[n]);
        #pragma unroll
        for (int m = 0; m < 4; ++m)
            #pragma unroll
            for (int n = 0; n < 4; ++n)
                acc[m][n] = __builtin_amdgcn_mfma_f32_16x16x32_bf16(a[m], b[n], acc[m][n], 0, 0, 0);
    }

    // complete row norms: reduce over the 4 lhi groups (lane bits 4,5)
    #pragma unroll
    for (int m = 0; m < 4; ++m) {
        amag[m] += __shfl_xor(amag[m], 16);
        amag[m] += __shfl_xor(amag[m], 32);
        bmag[m] += __shfl_xor(bmag[m], 16);
        bmag[m] += __shfl_xor(bmag[m], 32);
    }
    // now lane (llo,lhi): amag[m] = ||row i0+m*16+llo||^2, bmag[n] = ||row j0+n*16+llo||^2

    int tj[4];
    #pragma unroll
    for (int n = 0; n < 4; ++n) tj[n] = tgt[j0 + n * 16 + llo];

    const int slot = bj * 2 + wc;
    // C/D layout: col = lane&15 (j), row = (lane>>4)*4 + r (i)
    #pragma unroll
    for (int m = 0; m < 4; ++m) {
        const int ibase = i0 + m * 16 + lhi * 4;
        int4 ti4 = *reinterpret_cast<const int4*>(tgt + ibase);
        const int* tip = &ti4.x;
        f32x4 rs = {0.0f, 0.0f, 0.0f, 0.0f};
        #pragma unroll
        for (int r = 0; r < 4; ++r) {
            // mag of row ibase+r lives (replicated over lhi) in lanes with llo = lhi*4+r
            const float magir = __shfl(amag[m], lhi * 4 + r);
            const int ti = tip[r];
            float s = 0.0f;
            #pragma unroll
            for (int n = 0; n < 4; ++n) {
                float d2 = fmaxf(magir + bmag[n] - 2.0f * acc[m][n][r], 0.0f);
                float dist = __builtin_amdgcn_sqrtf(d2);
                s += (ti != tj[n]) ? __expf(MARGIN_F - dist) : 0.0f;
            }
            #pragma unroll
            for (int o = 1; o < 16; o <<= 1) s += __shfl_xor(s, o);
            rs[r] = s;
        }
        if (llo == 0)
            *reinterpret_cast<f32x4*>(negp + (size_t)slot * BN + ibase) = rs;
    }
}

// K2: fold 64 slot-partials into neg[i].
__global__ __launch_bounds__(256) void reduce_neg_kernel(
    const float* __restrict__ negp, float* __restrict__ neg)
{
    const int i = blockIdx.x * 256 + threadIdx.x;
    float s = 0.0f;
    #pragma unroll
    for (int k = 0; k < NSLOT; ++k) s += negp[(size_t)k * BN + i];
    neg[i] = s;
}

// K3: per-class loss. In-block compaction (R9) + fused fp32 reads / in-register mags.
__global__ __launch_bounds__(256) void loss_kernel(
    const float* __restrict__ score,
    const int* __restrict__ tgt,
    const float* __restrict__ neg,
    float2* __restrict__ part)
{
    const int c = blockIdx.x;
    const int tid = threadIdx.x;
    const int wid = tid >> 6, lane = tid & 63;

    // ---- stable compaction of rows with tgt==c into slist ----
    __shared__ int slist[256];
    __shared__ int wsum[4];
    __shared__ int snc;
    int4 tv[4];
    #pragma unroll
    for (int k = 0; k < 4; ++k)
        tv[k] = *reinterpret_cast<const int4*>(tgt + tid * 16 + k * 4);
    int cnt = 0;
    #pragma unroll
    for (int k = 0; k < 4; ++k) {
        const int* q = &tv[k].x;
        #pragma unroll
        for (int e = 0; e < 4; ++e) cnt += (q[e] == c) ? 1 : 0;
    }
    int inc = cnt;
    #pragma unroll
    for (int o = 1; o < 64; o <<= 1) {
        int u = __shfl_up(inc, o);
        if (lane >= o) inc += u;
    }
    if (lane == 63) wsum[wid] = inc;
    __syncthreads();
    int wpre = 0;
    #pragma unroll
    for (int w = 0; w < 4; ++w) wpre += (w < wid) ? wsum[w] : 0;
    if (tid == 255) snc = wpre + inc;
    int pos = wpre + inc - cnt;
    #pragma unroll
    for (int k = 0; k < 4; ++k) {
        const int* q = &tv[k].x;
        #pragma unroll
        for (int e = 0; e < 4; ++e) {
            if (q[e] == c && pos < 256) { slist[pos] = tid * 16 + k * 4 + e; ++pos; }
        }
    }
    __syncthreads();
    const int n_c = snc;

    const int wr = wid >> 1, wc = wid & 1;
    const int p0 = wr * 64, q0 = wc * 64;
    const int lhi = lane >> 4, llo = lane & 15;

    float lsum = 0.0f, lcnt = 0.0f;
    const bool active = (n_c > 0) && (wc >= wr) && (p0 < n_c) && (q0 < n_c);
    if (active) {
        int opA[4], opB[4];
        #pragma unroll
        for (int m = 0; m < 4; ++m)
            opA[m] = slist[min(p0 + m * 16 + llo, n_c - 1)];
        #pragma unroll
        for (int n = 0; n < 4; ++n)
            opB[n] = slist[min(q0 + n * 16 + llo, n_c - 1)];

        f32x4 acc[4][4] = {};
        float amag[4] = {0.f, 0.f, 0.f, 0.f};
        float bmag[4] = {0.f, 0.f, 0.f, 0.f};
        #pragma unroll
        for (int kk = 0; kk < 4; ++kk) {
            const int ke = kk * 32 + lhi * 8;
            bf16x8 a[4], b[4];
            #pragma unroll
            for (int m = 0; m < 4; ++m)
                a[m] = load_cvt8(score + (size_t)opA[m] * DD + ke, amag[m]);
            #pragma unroll
            for (int n = 0; n < 4; ++n)
                b[n] = load_cvt8(score + (size_t)opB[n] * DD + ke, bmag[n]);
            #pragma unroll
            for (int m = 0; m < 4; ++m)
                #pragma unroll
                for (int n = 0; n < 4; ++n)
                    acc[m][n] = __builtin_amdgcn_mfma_f32_16x16x32_bf16(a[m], b[n], acc[m][n], 0, 0, 0);
        }
        #pragma unroll
        for (int m = 0; m < 4; ++m) {
            amag[m] += __shfl_xor(amag[m], 16);
            amag[m] += __shfl_xor(amag[m], 32);
            bmag[m] += __shfl_xor(bmag[m], 16);
            bmag[m] += __shfl_xor(bmag[m], 32);
        }

        float nsj[4]; int qv[4];
        #pragma unroll
        for (int n = 0; n < 4; ++n) {
            qv[n] = q0 + n * 16 + llo;
            nsj[n] = neg[opB[n]];
        }

        #pragma unroll
        for (int m = 0; m < 4; ++m) {
            #pragma unroll
            for (int r = 0; r < 4; ++r) {
                const int p = p0 + m * 16 + lhi * 4 + r;
                const bool pv = (p < n_c);
                const int io = slist[min(p, n_c - 1)];
                const float magiv = __shfl(amag[m], lhi * 4 + r);
                const float nsi = neg[io];
                #pragma unroll
                for (int n = 0; n < 4; ++n) {
                    if (pv && qv[n] > p && qv[n] < n_c) {
                        float d2 = fmaxf(magiv + bmag[n] - 2.0f * acc[m][n][r], 0.0f);
                        float dist = __builtin_amdgcn_sqrtf(d2);
                        float ln = __logf(nsi + nsj[n]);
                        float uu = fmaxf(ln + dist, 0.0f);
                        lsum += uu * uu;
                        lcnt += 1.0f;
                    }
                }
            }
        }
    }

    #pragma unroll
    for (int o = 32; o > 0; o >>= 1) {
        lsum += __shfl_xor(lsum, o);
        lcnt += __shfl_xor(lcnt, o);
    }
    __shared__ float2 wpart[4];
    if (lane == 0) wpart[wid] = make_float2(lsum, lcnt);
    __syncthreads();
    if (tid == 0) {
        float s = 0.0f, cc = 0.0f;
        #pragma unroll
        for (int w = 0; w < 4; ++w) { s += wpart[w].x; cc += wpart[w].y; }
        part[c] = make_float2(s, cc);
    }
}

// K4: reduce 64 class partials -> scalar.
__global__ __launch_bounds__(64) void finalize_kernel(
    const float2* __restrict__ part, float* __restrict__ out)
{
    const int t = threadIdx.x;
    float2 p = part[t];
    float s = p.x, c = p.y;
    #pragma unroll
    for (int o = 32; o > 0; o >>= 1) {
        s += __shfl_xor(s, o);
        c += __shfl_xor(c, o);
    }
    if (t == 0) out[0] = s / (2.0f * fmaxf(c, 1.0f));
}

extern "C" void kernel_launch(void* const* d_in, const int* in_sizes, int n_in,
                              void* d_out, int out_size, void* d_ws, size_t ws_size,
                              hipStream_t stream) {
    const float* score = (const float*)d_in[0];
    const int* tgt = (const int*)d_in[1];
    float* out = (float*)d_out;

    char* ws = (char*)d_ws;
    float* negp = (float*)ws;                                // 64*4096*4 = 1 MB
    float* neg = negp + (size_t)NSLOT * BN;                  // 16 KB
    float2* part = (float2*)(neg + BN);                      // 512 B

    negsum_kernel<<<NSQ, 256, 0, stream>>>(score, tgt, negp);
    reduce_neg_kernel<<<BN / 256, 256, 0, stream>>>(negp, neg);
    loss_kernel<<<NCLS, 256, 0, stream>>>(score, tgt, neg, part);
    finalize_kernel<<<1, 64, 0, stream>>>(part, out);
}

// Round 14
// 57.610 us; speedup vs baseline: 4.7583x; 1.3672x over previous
//
#include <hip/hip_runtime.h>
#include <hip/hip_bf16.h>

#define BN 4096
#define DD 128
#define SD 136          // padded bf16 row stride (elems)
#define NCLS 64
#define MARGIN_F 1.0f
#define NSQ 1024        // 32x32 grid of 128x128 tiles
#define NGB 512         // launched blocks: 2/CU x 256 CU, all resident; 2 jobs each
#define NSLOT 64        // negp partial slots per row (32 bj x 2 wc)

typedef __attribute__((ext_vector_type(8))) short bf16x8;
typedef __attribute__((ext_vector_type(4))) float f32x4;

__device__ __forceinline__ unsigned short f2bf(float f) {
    __hip_bfloat16 h = __float2bfloat16(f);
    return *reinterpret_cast<unsigned short*>(&h);
}

// K1: fp32->bf16 convert (padded stride) + row squared norms.
__global__ __launch_bounds__(256) void prep_kernel(
    const float* __restrict__ score,
    unsigned short* __restrict__ sbf,
    float* __restrict__ mag)
{
    const int tid = threadIdx.x;
    const int w = tid >> 6, lane = tid & 63;
    const int row = blockIdx.x * 8 + w * 2 + (lane >> 5);
    const int l32 = lane & 31;
    float4 v = *reinterpret_cast<const float4*>(score + (size_t)row * DD + l32 * 4);
    ushort4 u;
    u.x = f2bf(v.x); u.y = f2bf(v.y); u.z = f2bf(v.z); u.w = f2bf(v.w);
    *reinterpret_cast<ushort4*>(sbf + (size_t)row * SD + l32 * 4) = u;
    float s = v.x * v.x + v.y * v.y + v.z * v.z + v.w * v.w;
    #pragma unroll
    for (int o = 16; o > 0; o >>= 1) s += __shfl_xor(s, o);
    if (l32 == 0) mag[row] = s;
}

// K2: neg partial sums. R9 body; 512 resident blocks x 2 in-kernel jobs
// (zero workgroup re-dispatch — the suspected fixed cost).
__global__ __launch_bounds__(256, 2) void negsum_kernel(
    const unsigned short* __restrict__ sbf,
    const float* __restrict__ mag,
    const int* __restrict__ tgt,
    float* __restrict__ negp)
{
    const int tid = threadIdx.x;
    const int wid = tid >> 6, lane = tid & 63;
    const int lhi = lane >> 4, llo = lane & 15;
    const int wr = wid >> 1, wc = wid & 1;

    #pragma unroll 1
    for (int job = blockIdx.x; job < NSQ; job += NGB) {
        const int bi = job & 31, bj = job >> 5;
        const int i0 = bi * 128 + wr * 64;
        const int j0 = bj * 128 + wc * 64;

        f32x4 acc[4][4] = {};
        #pragma unroll
        for (int kk = 0; kk < 4; ++kk) {
            const int koff = kk * 32 + lhi * 8;
            bf16x8 a[4], b[4];
            #pragma unroll
            for (int m = 0; m < 4; ++m)
                a[m] = *reinterpret_cast<const bf16x8*>(sbf + (size_t)(i0 + m * 16 + llo) * SD + koff);
            #pragma unroll
            for (int n = 0; n < 4; ++n)
                b[n] = *reinterpret_cast<const bf16x8*>(sbf + (size_t)(j0 + n * 16 + llo) * SD + koff);
            #pragma unroll
            for (int m = 0; m < 4; ++m)
                #pragma unroll
                for (int n = 0; n < 4; ++n)
                    acc[m][n] = __builtin_amdgcn_mfma_f32_16x16x32_bf16(a[m], b[n], acc[m][n], 0, 0, 0);
        }

        float magj[4]; int tj[4];
        #pragma unroll
        for (int n = 0; n < 4; ++n) {
            const int j = j0 + n * 16 + llo;
            magj[n] = mag[j];
            tj[n] = tgt[j];
        }

        const int slot = bj * 2 + wc;
        // C/D layout: col = lane&15 (j), row = (lane>>4)*4 + r (i)
        #pragma unroll
        for (int m = 0; m < 4; ++m) {
            const int ibase = i0 + m * 16 + lhi * 4;
            f32x4 magi = *reinterpret_cast<const f32x4*>(mag + ibase);
            int4 ti4 = *reinterpret_cast<const int4*>(tgt + ibase);
            const int* tip = &ti4.x;
            f32x4 rs = {0.0f, 0.0f, 0.0f, 0.0f};
            #pragma unroll
            for (int r = 0; r < 4; ++r) {
                const int ti = tip[r];
                float s = 0.0f;
                #pragma unroll
                for (int n = 0; n < 4; ++n) {
                    float d2 = fmaxf(magi[r] + magj[n] - 2.0f * acc[m][n][r], 0.0f);
                    float dist = __builtin_amdgcn_sqrtf(d2);
                    s += (ti != tj[n]) ? __expf(MARGIN_F - dist) : 0.0f;
                }
                #pragma unroll
                for (int o = 1; o < 16; o <<= 1) s += __shfl_xor(s, o);
                rs[r] = s;
            }
            if (llo == 0)
                *reinterpret_cast<f32x4*>(negp + (size_t)slot * BN + ibase) = rs;
        }
    }
}

// K3: fold 64 slot-partials into neg[i].
__global__ __launch_bounds__(256) void reduce_neg_kernel(
    const float* __restrict__ negp, float* __restrict__ neg)
{
    const int i = blockIdx.x * 256 + threadIdx.x;
    float s = 0.0f;
    #pragma unroll
    for (int k = 0; k < NSLOT; ++k) s += negp[(size_t)k * BN + i];
    neg[i] = s;
}

// K4: per-class loss with in-block stable compaction (R9).
__global__ __launch_bounds__(256) void loss_kernel(
    const unsigned short* __restrict__ sbf,
    const float* __restrict__ mag,
    const float* __restrict__ neg,
    const int* __restrict__ tgt,
    float2* __restrict__ part)
{
    const int c = blockIdx.x;
    const int tid = threadIdx.x;
    const int wid = tid >> 6, lane = tid & 63;

    __shared__ int slist[256];
    __shared__ int wsum[4];
    __shared__ int snc;
    int4 tv[4];
    #pragma unroll
    for (int k = 0; k < 4; ++k)
        tv[k] = *reinterpret_cast<const int4*>(tgt + tid * 16 + k * 4);
    int cnt = 0;
    #pragma unroll
    for (int k = 0; k < 4; ++k) {
        const int* q = &tv[k].x;
        #pragma unroll
        for (int e = 0; e < 4; ++e) cnt += (q[e] == c) ? 1 : 0;
    }
    int inc = cnt;
    #pragma unroll
    for (int o = 1; o < 64; o <<= 1) {
        int u = __shfl_up(inc, o);
        if (lane >= o) inc += u;
    }
    if (lane == 63) wsum[wid] = inc;
    __syncthreads();
    int wpre = 0;
    #pragma unroll
    for (int w = 0; w < 4; ++w) wpre += (w < wid) ? wsum[w] : 0;
    if (tid == 255) snc = wpre + inc;
    int pos = wpre + inc - cnt;
    #pragma unroll
    for (int k = 0; k < 4; ++k) {
        const int* q = &tv[k].x;
        #pragma unroll
        for (int e = 0; e < 4; ++e) {
            if (q[e] == c && pos < 256) { slist[pos] = tid * 16 + k * 4 + e; ++pos; }
        }
    }
    __syncthreads();
    const int n_c = snc;

    const int wr = wid >> 1, wc = wid & 1;
    const int p0 = wr * 64, q0 = wc * 64;
    const int lhi = lane >> 4, llo = lane & 15;

    float lsum = 0.0f, lcnt = 0.0f;
    const bool active = (n_c > 0) && (wc >= wr) && (p0 < n_c) && (q0 < n_c);
    if (active) {
        int opA[4], opB[4];
        #pragma unroll
        for (int m = 0; m < 4; ++m)
            opA[m] = slist[min(p0 + m * 16 + llo, n_c - 1)];
        #pragma unroll
        for (int n = 0; n < 4; ++n)
            opB[n] = slist[min(q0 + n * 16 + llo, n_c - 1)];

        f32x4 acc[4][4] = {};
        #pragma unroll
        for (int kk = 0; kk < 4; ++kk) {
            const int koff = kk * 32 + lhi * 8;
            bf16x8 a[4], b[4];
            #pragma unroll
            for (int m = 0; m < 4; ++m)
                a[m] = *reinterpret_cast<const bf16x8*>(sbf + (size_t)opA[m] * SD + koff);
            #pragma unroll
            for (int n = 0; n < 4; ++n)
                b[n] = *reinterpret_cast<const bf16x8*>(sbf + (size_t)opB[n] * SD + koff);
            #pragma unroll
            for (int m = 0; m < 4; ++m)
                #pragma unroll
                for (int n = 0; n < 4; ++n)
                    acc[m][n] = __builtin_amdgcn_mfma_f32_16x16x32_bf16(a[m], b[n], acc[m][n], 0, 0, 0);
        }

        float magjv[4], nsj[4]; int qv[4];
        #pragma unroll
        for (int n = 0; n < 4; ++n) {
            qv[n] = q0 + n * 16 + llo;
            magjv[n] = mag[opB[n]];
            nsj[n] = neg[opB[n]];
        }

        #pragma unroll
        for (int m = 0; m < 4; ++m) {
            #pragma unroll
            for (int r = 0; r < 4; ++r) {
                const int p = p0 + m * 16 + lhi * 4 + r;
                const bool pv = (p < n_c);
                const int io = slist[min(p, n_c - 1)];
                const float magiv = mag[io];
                const float nsi = neg[io];
                #pragma unroll
                for (int n = 0; n < 4; ++n) {
                    if (pv && qv[n] > p && qv[n] < n_c) {
                        float d2 = fmaxf(magiv + magjv[n] - 2.0f * acc[m][n][r], 0.0f);
                        float dist = __builtin_amdgcn_sqrtf(d2);
                        float ln = __logf(nsi + nsj[n]);
                        float uu = fmaxf(ln + dist, 0.0f);
                        lsum += uu * uu;
                        lcnt += 1.0f;
                    }
                }
            }
        }
    }

    #pragma unroll
    for (int o = 32; o > 0; o >>= 1) {
        lsum += __shfl_xor(lsum, o);
        lcnt += __shfl_xor(lcnt, o);
    }
    __shared__ float2 wpart[4];
    if (lane == 0) wpart[wid] = make_float2(lsum, lcnt);
    __syncthreads();
    if (tid == 0) {
        float s = 0.0f, cc = 0.0f;
        #pragma unroll
        for (int w = 0; w < 4; ++w) { s += wpart[w].x; cc += wpart[w].y; }
        part[c] = make_float2(s, cc);
    }
}

// K5: reduce 64 class partials -> scalar.
__global__ __launch_bounds__(64) void finalize_kernel(
    const float2* __restrict__ part, float* __restrict__ out)
{
    const int t = threadIdx.x;
    float2 p = part[t];
    float s = p.x, c = p.y;
    #pragma unroll
    for (int o = 32; o > 0; o >>= 1) {
        s += __shfl_xor(s, o);
        c += __shfl_xor(c, o);
    }
    if (t == 0) out[0] = s / (2.0f * fmaxf(c, 1.0f));
}

extern "C" void kernel_launch(void* const* d_in, const int* in_sizes, int n_in,
                              void* d_out, int out_size, void* d_ws, size_t ws_size,
                              hipStream_t stream) {
    const float* score = (const float*)d_in[0];
    const int* tgt = (const int*)d_in[1];
    float* out = (float*)d_out;

    char* ws = (char*)d_ws;
    unsigned short* sbf = (unsigned short*)ws;               // 4096*136*2 ≈ 1.09 MB
    float* mag = (float*)(ws + (size_t)BN * SD * 2 + 64);    // 16 KB
    float* neg = mag + BN;                                   // 16 KB
    float* negp = neg + BN;                                  // 64*4096*4 = 1 MB
    float2* part = (float2*)(negp + (size_t)NSLOT * BN);     // 512 B

    prep_kernel<<<512, 256, 0, stream>>>(score, sbf, mag);
    negsum_kernel<<<NGB, 256, 0, stream>>>(sbf, mag, tgt, negp);
    reduce_neg_kernel<<<BN / 256, 256, 0, stream>>>(negp, neg);
    loss_kernel<<<NCLS, 256, 0, stream>>>(sbf, mag, neg, tgt, part);
    finalize_kernel<<<1, 64, 0, stream>>>(part, out);
}

// Round 15
// 53.532 us; speedup vs baseline: 5.1207x; 1.0762x over previous
//
#include <hip/hip_runtime.h>
#include <hip/hip_bf16.h>

#define BN 4096
#define DD 128
#define SD 136          // padded bf16 row stride (elems)
#define NCLS 64
#define MARGIN_F 1.0f
#define NTRI 528        // 32*33/2 triangle tiles of 128x128 (bi <= bj)
#define NSLOT 64        // negp partial slots per row

typedef __attribute__((ext_vector_type(8))) short bf16x8;
typedef __attribute__((ext_vector_type(4))) float f32x4;

__device__ __forceinline__ unsigned short f2bf(float f) {
    __hip_bfloat16 h = __float2bfloat16(f);
    return *reinterpret_cast<unsigned short*>(&h);
}

// K1: fp32->bf16 convert (padded stride) + row squared norms.
__global__ __launch_bounds__(256) void prep_kernel(
    const float* __restrict__ score,
    unsigned short* __restrict__ sbf,
    float* __restrict__ mag)
{
    const int tid = threadIdx.x;
    const int w = tid >> 6, lane = tid & 63;
    const int row = blockIdx.x * 8 + w * 2 + (lane >> 5);
    const int l32 = lane & 31;
    float4 v = *reinterpret_cast<const float4*>(score + (size_t)row * DD + l32 * 4);
    ushort4 u;
    u.x = f2bf(v.x); u.y = f2bf(v.y); u.z = f2bf(v.z); u.w = f2bf(v.w);
    *reinterpret_cast<ushort4*>(sbf + (size_t)row * SD + l32 * 4) = u;
    float s = v.x * v.x + v.y * v.y + v.z * v.z + v.w * v.w;
    #pragma unroll
    for (int o = 16; o > 0; o >>= 1) s += __shfl_xor(s, o);
    if (l32 == 0) mag[row] = s;
}

// K2: neg partial sums over the TRIANGLE (bi<=bj), R9 fat-wave block structure.
// Off-diagonal tiles emit row sums (slot 2bj+wc) AND col sums (slot 2bi+wr).
// For each panel p these slot sets partition [0,64) exactly — no zeroing needed.
__global__ __launch_bounds__(256, 2) void negsum_kernel(
    const unsigned short* __restrict__ sbf,
    const float* __restrict__ mag,
    const int* __restrict__ tgt,
    float* __restrict__ negp)
{
    const int idx = blockIdx.x;
    const int tid = threadIdx.x;
    const int wid = tid >> 6, lane = tid & 63;
    const int lhi = lane >> 4, llo = lane & 15;
    const int wr = wid >> 1, wc = wid & 1;

    // decode triangle tile (bi <= bj) in a 32x32 tile grid; off(bi)=bi*(65-bi)/2
    int bi = (int)((65.0f - __builtin_amdgcn_sqrtf(4225.0f - 8.0f * (float)idx)) * 0.5f);
    bi = max(0, min(bi, 31));
    while (bi * (65 - bi) / 2 > idx) --bi;
    while ((bi + 1) * (64 - bi) / 2 <= idx) ++bi;
    const int bj = bi + (idx - bi * (65 - bi) / 2);
    const bool diag = (bi == bj);

    const int i0 = bi * 128 + wr * 64;
    const int j0 = bj * 128 + wc * 64;

    f32x4 acc[4][4] = {};
    #pragma unroll
    for (int kk = 0; kk < 4; ++kk) {
        const int koff = kk * 32 + lhi * 8;
        bf16x8 a[4], b[4];
        #pragma unroll
        for (int m = 0; m < 4; ++m)
            a[m] = *reinterpret_cast<const bf16x8*>(sbf + (size_t)(i0 + m * 16 + llo) * SD + koff);
        #pragma unroll
        for (int n = 0; n < 4; ++n)
            b[n] = *reinterpret_cast<const bf16x8*>(sbf + (size_t)(j0 + n * 16 + llo) * SD + koff);
        #pragma unroll
        for (int m = 0; m < 4; ++m)
            #pragma unroll
            for (int n = 0; n < 4; ++n)
                acc[m][n] = __builtin_amdgcn_mfma_f32_16x16x32_bf16(a[m], b[n], acc[m][n], 0, 0, 0);
    }

    float magj[4]; int tj[4];
    #pragma unroll
    for (int n = 0; n < 4; ++n) {
        const int j = j0 + n * 16 + llo;
        magj[n] = mag[j];
        tj[n] = tgt[j];
    }

    float cs[4] = {0.0f, 0.0f, 0.0f, 0.0f};   // per-lane partial col sums
    const int rslot = bj * 2 + wc;
    // C/D layout: col = lane&15 (j), row = (lane>>4)*4 + r (i)
    #pragma unroll
    for (int m = 0; m < 4; ++m) {
        const int ibase = i0 + m * 16 + lhi * 4;
        f32x4 magi = *reinterpret_cast<const f32x4*>(mag + ibase);
        int4 ti4 = *reinterpret_cast<const int4*>(tgt + ibase);
        const int* tip = &ti4.x;
        f32x4 rs = {0.0f, 0.0f, 0.0f, 0.0f};
        #pragma unroll
        for (int r = 0; r < 4; ++r) {
            const int ti = tip[r];
            float s = 0.0f;
            #pragma unroll
            for (int n = 0; n < 4; ++n) {
                float d2 = fmaxf(magi[r] + magj[n] - 2.0f * acc[m][n][r], 0.0f);
                float dist = __builtin_amdgcn_sqrtf(d2);
                float v = (ti != tj[n]) ? __expf(MARGIN_F - dist) : 0.0f;
                s += v;
                cs[n] += v;
            }
            #pragma unroll
            for (int o = 1; o < 16; o <<= 1) s += __shfl_xor(s, o);
            rs[r] = s;
        }
        if (llo == 0)
            *reinterpret_cast<f32x4*>(negp + (size_t)rslot * BN + ibase) = rs;
    }

    if (!diag) {
        // complete col sums over the wave's 64 rows (reduce across lhi groups)
        #pragma unroll
        for (int n = 0; n < 4; ++n) {
            cs[n] += __shfl_xor(cs[n], 16);
            cs[n] += __shfl_xor(cs[n], 32);
        }
        const int cslot = bi * 2 + wr;
        if (lhi == 0) {
            #pragma unroll
            for (int n = 0; n < 4; ++n)
                negp[(size_t)cslot * BN + j0 + n * 16 + llo] = cs[n];
        }
    }
}

// K3: fold 64 slot-partials into neg[i].
__global__ __launch_bounds__(256) void reduce_neg_kernel(
    const float* __restrict__ negp, float* __restrict__ neg)
{
    const int i = blockIdx.x * 256 + threadIdx.x;
    float s = 0.0f;
    #pragma unroll
    for (int k = 0; k < NSLOT; ++k) s += negp[(size_t)k * BN + i];
    neg[i] = s;
}

// K4: per-class loss with in-block stable compaction (R9).
__global__ __launch_bounds__(256) void loss_kernel(
    const unsigned short* __restrict__ sbf,
    const float* __restrict__ mag,
    const float* __restrict__ neg,
    const int* __restrict__ tgt,
    float2* __restrict__ part)
{
    const int c = blockIdx.x;
    const int tid = threadIdx.x;
    const int wid = tid >> 6, lane = tid & 63;

    __shared__ int slist[256];
    __shared__ int wsum[4];
    __shared__ int snc;
    int4 tv[4];
    #pragma unroll
    for (int k = 0; k < 4; ++k)
        tv[k] = *reinterpret_cast<const int4*>(tgt + tid * 16 + k * 4);
    int cnt = 0;
    #pragma unroll
    for (int k = 0; k < 4; ++k) {
        const int* q = &tv[k].x;
        #pragma unroll
        for (int e = 0; e < 4; ++e) cnt += (q[e] == c) ? 1 : 0;
    }
    int inc = cnt;
    #pragma unroll
    for (int o = 1; o < 64; o <<= 1) {
        int u = __shfl_up(inc, o);
        if (lane >= o) inc += u;
    }
    if (lane == 63) wsum[wid] = inc;
    __syncthreads();
    int wpre = 0;
    #pragma unroll
    for (int w = 0; w < 4; ++w) wpre += (w < wid) ? wsum[w] : 0;
    if (tid == 255) snc = wpre + inc;
    int pos = wpre + inc - cnt;
    #pragma unroll
    for (int k = 0; k < 4; ++k) {
        const int* q = &tv[k].x;
        #pragma unroll
        for (int e = 0; e < 4; ++e) {
            if (q[e] == c && pos < 256) { slist[pos] = tid * 16 + k * 4 + e; ++pos; }
        }
    }
    __syncthreads();
    const int n_c = snc;

    const int wr = wid >> 1, wc = wid & 1;
    const int p0 = wr * 64, q0 = wc * 64;
    const int lhi = lane >> 4, llo = lane & 15;

    float lsum = 0.0f, lcnt = 0.0f;
    const bool active = (n_c > 0) && (wc >= wr) && (p0 < n_c) && (q0 < n_c);
    if (active) {
        int opA[4], opB[4];
        #pragma unroll
        for (int m = 0; m < 4; ++m)
            opA[m] = slist[min(p0 + m * 16 + llo, n_c - 1)];
        #pragma unroll
        for (int n = 0; n < 4; ++n)
            opB[n] = slist[min(q0 + n * 16 + llo, n_c - 1)];

        f32x4 acc[4][4] = {};
        #pragma unroll
        for (int kk = 0; kk < 4; ++kk) {
            const int koff = kk * 32 + lhi * 8;
            bf16x8 a[4], b[4];
            #pragma unroll
            for (int m = 0; m < 4; ++m)
                a[m] = *reinterpret_cast<const bf16x8*>(sbf + (size_t)opA[m] * SD + koff);
            #pragma unroll
            for (int n = 0; n < 4; ++n)
                b[n] = *reinterpret_cast<const bf16x8*>(sbf + (size_t)opB[n] * SD + koff);
            #pragma unroll
            for (int m = 0; m < 4; ++m)
                #pragma unroll
                for (int n = 0; n < 4; ++n)
                    acc[m][n] = __builtin_amdgcn_mfma_f32_16x16x32_bf16(a[m], b[n], acc[m][n], 0, 0, 0);
        }

        float magjv[4], nsj[4]; int qv[4];
        #pragma unroll
        for (int n = 0; n < 4; ++n) {
            qv[n] = q0 + n * 16 + llo;
            magjv[n] = mag[opB[n]];
            nsj[n] = neg[opB[n]];
        }

        #pragma unroll
        for (int m = 0; m < 4; ++m) {
            #pragma unroll
            for (int r = 0; r < 4; ++r) {
                const int p = p0 + m * 16 + lhi * 4 + r;
                const bool pv = (p < n_c);
                const int io = slist[min(p, n_c - 1)];
                const float magiv = mag[io];
                const float nsi = neg[io];
                #pragma unroll
                for (int n = 0; n < 4; ++n) {
                    if (pv && qv[n] > p && qv[n] < n_c) {
                        float d2 = fmaxf(magiv + magjv[n] - 2.0f * acc[m][n][r], 0.0f);
                        float dist = __builtin_amdgcn_sqrtf(d2);
                        float ln = __logf(nsi + nsj[n]);
                        float uu = fmaxf(ln + dist, 0.0f);
                        lsum += uu * uu;
                        lcnt += 1.0f;
                    }
                }
            }
        }
    }

    #pragma unroll
    for (int o = 32; o > 0; o >>= 1) {
        lsum += __shfl_xor(lsum, o);
        lcnt += __shfl_xor(lcnt, o);
    }
    __shared__ float2 wpart[4];
    if (lane == 0) wpart[wid] = make_float2(lsum, lcnt);
    __syncthreads();
    if (tid == 0) {
        float s = 0.0f, cc = 0.0f;
        #pragma unroll
        for (int w = 0; w < 4; ++w) { s += wpart[w].x; cc += wpart[w].y; }
        part[c] = make_float2(s, cc);
    }
}

// K5: reduce 64 class partials -> scalar.
__global__ __launch_bounds__(64) void finalize_kernel(
    const float2* __restrict__ part, float* __restrict__ out)
{
    const int t = threadIdx.x;
    float2 p = part[t];
    float s = p.x, c = p.y;
    #pragma unroll
    for (int o = 32; o > 0; o >>= 1) {
        s += __shfl_xor(s, o);
        c += __shfl_xor(c, o);
    }
    if (t == 0) out[0] = s / (2.0f * fmaxf(c, 1.0f));
}

extern "C" void kernel_launch(void* const* d_in, const int* in_sizes, int n_in,
                              void* d_out, int out_size, void* d_ws, size_t ws_size,
                              hipStream_t stream) {
    const float* score = (const float*)d_in[0];
    const int* tgt = (const int*)d_in[1];
    float* out = (float*)d_out;

    char* ws = (char*)d_ws;
    unsigned short* sbf = (unsigned short*)ws;               // 4096*136*2 ≈ 1.09 MB
    float* mag = (float*)(ws + (size_t)BN * SD * 2 + 64);    // 16 KB
    float* neg = mag + BN;                                   // 16 KB
    float* negp = neg + BN;                                  // 64*4096*4 = 1 MB
    float2* part = (float2*)(negp + (size_t)NSLOT * BN);     // 512 B

    prep_kernel<<<512, 256, 0, stream>>>(score, sbf, mag);
    negsum_kernel<<<NTRI, 256, 0, stream>>>(sbf, mag, tgt, negp);
    reduce_neg_kernel<<<BN / 256, 256, 0, stream>>>(negp, neg);
    loss_kernel<<<NCLS, 256, 0, stream>>>(sbf, mag, neg, tgt, part);
    finalize_kernel<<<1, 64, 0, stream>>>(part, out);
}